// Round 9
// baseline (524.765 us; speedup 1.0000x reference)
//
#include <hip/hip_runtime.h>
#include <hip/hip_bf16.h>
#include <math.h>

#define SEQ 512
#define DM  256
#define NH  8

typedef __attribute__((ext_vector_type(4))) float  f32x4;
typedef __attribute__((ext_vector_type(8))) __bf16 bf16x8;
typedef __attribute__((ext_vector_type(8))) short  s16x8;

__device__ __forceinline__ short fb(float x) {
  __bf16 h = (__bf16)x;
  return __builtin_bit_cast(short, h);
}
__device__ __forceinline__ unsigned short f2bf(float f) {
  unsigned int u = __builtin_bit_cast(unsigned int, f);
  u += 0x7fffu + ((u >> 16) & 1u);
  return (unsigned short)(u >> 16);
}
__device__ __forceinline__ float bf2f(unsigned short h) {
  unsigned int u = ((unsigned int)h) << 16;
  return __builtin_bit_cast(float, u);
}
__device__ __forceinline__ s16x8 cvt8(float4 a, float4 b) {
  s16x8 o;
  o[0]=fb(a.x); o[1]=fb(a.y); o[2]=fb(a.z); o[3]=fb(a.w);
  o[4]=fb(b.x); o[5]=fb(b.y); o[6]=fb(b.z); o[7]=fb(b.w);
  return o;
}
// async global->LDS, 16B/lane; dest is wave-uniform base (+lane*16 by HW)
__device__ __forceinline__ void gll16(const void* g, void* ldsbase) {
  __builtin_amdgcn_global_load_lds((const __attribute__((address_space(1))) void*)g,
                                   (__attribute__((address_space(3))) void*)ldsbase,
                                   16, 0, 0);
}

// ---------------------------------------------------------------------------
// kconv: f32 -> bf16 streaming convert (grid*256*32 elements)
__global__ __launch_bounds__(256) void kconv(const float* __restrict__ src,
                                             unsigned short* __restrict__ dst) {
  size_t base = ((size_t)blockIdx.x * 256 + threadIdx.x) * 32;
  #pragma unroll
  for (int u = 0; u < 4; u++) {
    float4 a = *(const float4*)(src + base + u * 8);
    float4 b = *(const float4*)(src + base + u * 8 + 4);
    *(s16x8*)(dst + base + u * 8) = cvt8(a, b);
  }
}

// ---------------------------------------------------------------------------
// K0: blocks 0..31 convert k (f32->bf16); blocks 32..63 transpose v -> vT bf16
__global__ __launch_bounds__(256) void k0_convert(const float* __restrict__ kin,
                                                  const float* __restrict__ vin,
                                                  unsigned short* __restrict__ kbf,
                                                  unsigned short* __restrict__ vT) {
  __shared__ unsigned short tl[64][72];
  int b = blockIdx.x, t = threadIdx.x;
  if (b < 32) {
    int base = b * 4096 + t * 16;
    float4 a0 = *(const float4*)(kin + base);
    float4 a1 = *(const float4*)(kin + base + 4);
    float4 a2 = *(const float4*)(kin + base + 8);
    float4 a3 = *(const float4*)(kin + base + 12);
    *(s16x8*)(kbf + base)     = cvt8(a0, a1);
    *(s16x8*)(kbf + base + 8) = cvt8(a2, a3);
  } else {
    int tb = b - 32;
    int i0 = (tb >> 2) * 64;
    int m0 = (tb & 3) * 64;
    int r = t >> 2, cq = t & 3;
    #pragma unroll
    for (int u = 0; u < 4; u++) {
      float4 x = *(const float4*)(vin + (size_t)(i0 + r) * DM + m0 + cq * 16 + u * 4);
      tl[cq*16 + u*4 + 0][r] = (unsigned short)fb(x.x);
      tl[cq*16 + u*4 + 1][r] = (unsigned short)fb(x.y);
      tl[cq*16 + u*4 + 2][r] = (unsigned short)fb(x.z);
      tl[cq*16 + u*4 + 3][r] = (unsigned short)fb(x.w);
    }
    __syncthreads();
    int mm = t >> 2;
    s16x8 w0, w1;
    #pragma unroll
    for (int e = 0; e < 8; e++) { w0[e] = tl[mm][cq*16 + e]; w1[e] = tl[mm][cq*16 + 8 + e]; }
    *(s16x8*)(vT + (size_t)(m0 + mm) * SEQ + i0 + cq * 16)     = w0;
    *(s16x8*)(vT + (size_t)(m0 + mm) * SEQ + i0 + cq * 16 + 8) = w1;
  }
}

// ---------------------------------------------------------------------------
// K1: qp = q @ Wq^T  (f32 + bf16 outputs)
__global__ __launch_bounds__(256) void k1_qproj(const float* __restrict__ q,
                                                const float* __restrict__ Wq,
                                                float* __restrict__ qpf,
                                                unsigned short* __restrict__ qpb) {
  __shared__ __align__(16) float qrow[DM];
  int i = blockIdx.x, t = threadIdx.x;
  if (t < 64) *(float4*)&qrow[t*4] = *(const float4*)(q + (size_t)i * DM + t * 4);
  __syncthreads();
  int w = t >> 6, lane = t & 63;
  for (int jj = 0; jj < 64; jj++) {
    int j = w * 64 + jj;
    float4 wv = *(const float4*)(Wq + (size_t)j * DM + lane * 4);
    float s = wv.x*qrow[lane*4] + wv.y*qrow[lane*4+1] + wv.z*qrow[lane*4+2] + wv.w*qrow[lane*4+3];
    #pragma unroll
    for (int off = 32; off; off >>= 1) s += __shfl_xor(s, off);
    if (lane == 0) { qpf[(size_t)i*DM + j] = s; qpb[(size_t)i*DM + j] = f2bf(s); }
  }
}

// ---------------------------------------------------------------------------
// ka7: r6 step-structure at 4 blocks/CU. Per block (head,jsplit,itile): 2 j's,
// each 4 kt steps: {barrier; gll16 B (32KB linear, inv-swz src); stage scaled
// A (qp[i,:]*qp[i,j] -> bf16, XOR-swz 8KB LDS); barrier; 32 MFMA/wave}.
// Scale folded into A => acc accumulates across j directly.
// atomicAdd into f32 af (each addr hit by 16 jsplits, distinct-lane coalesced).
// grid 1024 = head(8,XCD) x jsplit(16) x itile(8); LDS 40KB; VGPR<=128.
__global__ __launch_bounds__(256, 4) void ka7(const unsigned short* __restrict__ Wkb,
                                              const float* __restrict__ qpf,
                                              float* __restrict__ af) {
  __shared__ __align__(16) unsigned short lB[256 * 64];   // 32KB, linear (gll16)
  __shared__ __align__(16) unsigned short lAc[64 * 64];   // 8KB, XOR-swizzled
  int bid = blockIdx.x;
  int head = bid & 7, rest = bid >> 3;
  int jsplit = rest >> 3, itile = rest & 7;          // jsplit 0..15
  int m0 = itile * 64;
  int t = threadIdx.x, w = t >> 6, lane = t & 63;
  int r = lane & 15, hi = lane >> 4;
  int srow = t >> 2, so = (t & 3) * 32;              // A-staging: byte offsets
  const int jbase = head * 32 + jsplit * 2;

  f32x4 acc[4][4] = {};
  for (int jj = 0; jj < 2; jj++) {
    int jcol = jbase + jj;
    const unsigned short* Bj = Wkb + (size_t)jcol * 65536;
    for (int kt = 0; kt < 4; kt++) {
      __syncthreads();                               // prev reads done
      #pragma unroll
      for (int it = 0; it < 8; it++) {               // lB: 256x64 bf16
        int chunk = w * 8 + it;
        int row = chunk * 8 + (lane >> 3);
        int cb = ((lane & 7) * 16) ^ ((row & 7) << 4);
        gll16((const char*)(Bj + (size_t)row * 256 + kt * 64) + cb,
              (char*)lB + chunk * 1024);
      }
      { // stage scaled A: 64x64, qp*qp[i,jcol], f32->bf16, swz write
        float scal = qpf[(size_t)(m0 + srow) * DM + jcol];
        const float* src = qpf + (size_t)(m0 + srow) * DM + kt * 64 + (t & 3) * 16;
        float4 x0 = *(const float4*)src,       x1 = *(const float4*)(src + 4);
        float4 x2 = *(const float4*)(src + 8), x3 = *(const float4*)(src + 12);
        x0.x*=scal; x0.y*=scal; x0.z*=scal; x0.w*=scal;
        x1.x*=scal; x1.y*=scal; x1.z*=scal; x1.w*=scal;
        x2.x*=scal; x2.y*=scal; x2.z*=scal; x2.w*=scal;
        x3.x*=scal; x3.y*=scal; x3.z*=scal; x3.w*=scal;
        int swz = (srow & 7) << 4;
        *(s16x8*)((char*)lAc + srow*128 + (so ^ swz))        = cvt8(x0, x1);
        *(s16x8*)((char*)lAc + srow*128 + ((so + 16) ^ swz)) = cvt8(x2, x3);
      }
      __syncthreads();                               // drains vmcnt + lgkm
      #pragma unroll
      for (int kk = 0; kk < 2; kk++) {
        int kb = (kk*32 + hi*8) * 2;                 // byte col
        bf16x8 afr[4], bfr[4];
        #pragma unroll
        for (int mf = 0; mf < 4; mf++) {
          int row = mf*16 + r;
          afr[mf] = *(const bf16x8*)((const char*)lAc + row*128 + (kb ^ ((row & 7) << 4)));
        }
        #pragma unroll
        for (int nf = 0; nf < 4; nf++) {
          int bn = w*64 + nf*16 + r;
          bfr[nf] = *(const bf16x8*)((const char*)lB + bn*128 + (kb ^ ((bn & 7) << 4)));
        }
        #pragma unroll
        for (int mf = 0; mf < 4; mf++)
          #pragma unroll
          for (int nf = 0; nf < 4; nf++)
            acc[mf][nf] = __builtin_amdgcn_mfma_f32_16x16x32_bf16(afr[mf], bfr[nf], acc[mf][nf], 0, 0, 0);
      }
    }
  }
  #pragma unroll
  for (int mf = 0; mf < 4; mf++)
    #pragma unroll
    for (int nf = 0; nf < 4; nf++)
      #pragma unroll
      for (int qq = 0; qq < 4; qq++)
        atomicAdd(&af[((size_t)head * SEQ + m0 + mf*16 + hi*4 + qq) * DM + w*64 + nf*16 + r],
                  acc[mf][nf][qq]);
}

// ---------------------------------------------------------------------------
// ko7: r6 step-structure, 32KB LDS (B only), A-frags direct from L1-hot qpb.
// Per block: 2 j's x 4 kt: {barrier; gll16 B; load 8 A-frags; barrier; 32 MFMA};
// per-j epilogue: out[i,j] += sum_b U_j[i,b]*w (global w, shfl-reduce, atomic).
// grid 1024 = head(8,XCD) x jsplit(16) x itile(8); 4+ blocks/CU.
__global__ __launch_bounds__(256, 4) void ko7(const unsigned short* __restrict__ Wvb,
                                              const unsigned short* __restrict__ qpb,
                                              const unsigned short* __restrict__ wbf,
                                              float* __restrict__ out) {
  __shared__ __align__(16) unsigned short lB[256 * 64];   // 32KB, linear (gll16)
  int bid = blockIdx.x;
  int head = bid & 7, rest = bid >> 3;
  int jsplit = rest >> 3, itile = rest & 7;
  int m0 = itile * 64;
  int t = threadIdx.x, w = t >> 6, lane = t & 63;
  int r = lane & 15, hi = lane >> 4;
  const int jbase = head * 32 + jsplit * 2;

  for (int jj = 0; jj < 2; jj++) {
    int jcol = jbase + jj;
    const unsigned short* Bj = Wvb + (size_t)jcol * 65536;
    f32x4 tmp[4][4] = {};
    for (int kt = 0; kt < 4; kt++) {
      __syncthreads();
      #pragma unroll
      for (int it = 0; it < 8; it++) {
        int chunk = w * 8 + it;
        int row = chunk * 8 + (lane >> 3);
        int cb = ((lane & 7) * 16) ^ ((row & 7) << 4);
        gll16((const char*)(Bj + (size_t)row * 256 + kt * 64) + cb,
              (char*)lB + chunk * 1024);
      }
      bf16x8 afr[2][4];
      #pragma unroll
      for (int kk = 0; kk < 2; kk++)
        #pragma unroll
        for (int mf = 0; mf < 4; mf++)
          afr[kk][mf] = *(const bf16x8*)(qpb + (size_t)(m0 + mf*16 + r) * 256
                                         + kt*64 + kk*32 + hi*8);
      __syncthreads();
      #pragma unroll
      for (int kk = 0; kk < 2; kk++) {
        int kb = (kk*32 + hi*8) * 2;
        bf16x8 bfr[4];
        #pragma unroll
        for (int nf = 0; nf < 4; nf++) {
          int bn = w*64 + nf*16 + r;
          bfr[nf] = *(const bf16x8*)((const char*)lB + bn*128 + (kb ^ ((bn & 7) << 4)));
        }
        #pragma unroll
        for (int mf = 0; mf < 4; mf++)
          #pragma unroll
          for (int nf = 0; nf < 4; nf++)
            tmp[mf][nf] = __builtin_amdgcn_mfma_f32_16x16x32_bf16(afr[kk][mf], bfr[nf], tmp[mf][nf], 0, 0, 0);
      }
    }
    #pragma unroll
    for (int mf = 0; mf < 4; mf++)
      #pragma unroll
      for (int qq = 0; qq < 4; qq++) {
        int rloc = mf*16 + hi*4 + qq;
        const unsigned short* wrow = wbf + ((size_t)head * SEQ + m0 + rloc) * DM + w*64;
        float pp = 0.f;
        #pragma unroll
        for (int nf = 0; nf < 4; nf++)
          pp += tmp[mf][nf][qq] * bf2f(wrow[nf*16 + r]);
        pp += __shfl_xor(pp, 1);
        pp += __shfl_xor(pp, 2);
        pp += __shfl_xor(pp, 4);
        pp += __shfl_xor(pp, 8);
        if (r == 0) atomicAdd(&out[(size_t)(m0 + rloc) * DM + jcol], pp);
      }
  }
}

// ---------------------------------------------------------------------------
// Small 64x64-tile NT GEMM: C[M,N] = A[M,K] * B[N,K]^T, 4 waves (2x2)
template<int CONVA, int OUTBF>
__global__ __launch_bounds__(256) void gemm_small(const void* __restrict__ Ap,
                                                  const unsigned short* __restrict__ B,
                                                  void* __restrict__ Cp,
                                                  int M, int N, int K, int nMtiles) {
  __shared__ __align__(16) unsigned short lA[64 * 72];
  __shared__ __align__(16) unsigned short lB[64 * 72];
  int bid = blockIdx.x;
  int mtile = bid % nMtiles, ntile = bid / nMtiles;
  int m0 = mtile * 64, n0 = ntile * 64;
  int t = threadIdx.x, w = t >> 6, lane = t & 63;
  int wr = w >> 1, wcc = w & 1;
  f32x4 acc[2][2] = {};
  for (int kt = 0; kt < K; kt += 64) {
    __syncthreads();
    #pragma unroll
    for (int rep = 0; rep < 2; rep++) {
      int sc = rep * 256 + t;
      int row = sc >> 3, c8 = sc & 7;
      if (CONVA) {
        const float* src = (const float*)Ap + (size_t)(m0 + row) * K + kt + c8 * 8;
        float4 u0 = *(const float4*)src, u1 = *(const float4*)(src + 4);
        *(s16x8*)&lA[row * 72 + c8 * 8] = cvt8(u0, u1);
      } else {
        *(s16x8*)&lA[row * 72 + c8 * 8] =
            *(const s16x8*)((const unsigned short*)Ap + (size_t)(m0 + row) * K + kt + c8 * 8);
      }
      *(s16x8*)&lB[row * 72 + c8 * 8] = *(const s16x8*)(B + (size_t)(n0 + row) * K + kt + c8 * 8);
    }
    __syncthreads();
    #pragma unroll
    for (int kk = 0; kk < 2; kk++) {
      int r = lane & 15, kc = kk * 32 + (lane >> 4) * 8;
      bf16x8 afr[2], bfr[2];
      #pragma unroll
      for (int mf = 0; mf < 2; mf++) afr[mf] = *(const bf16x8*)&lA[(wr*32 + mf*16 + r) * 72 + kc];
      #pragma unroll
      for (int nf = 0; nf < 2; nf++) bfr[nf] = *(const bf16x8*)&lB[(wcc*32 + nf*16 + r) * 72 + kc];
      #pragma unroll
      for (int mf = 0; mf < 2; mf++)
        #pragma unroll
        for (int nf = 0; nf < 2; nf++)
          acc[mf][nf] = __builtin_amdgcn_mfma_f32_16x16x32_bf16(afr[mf], bfr[nf], acc[mf][nf], 0, 0, 0);
    }
  }
  int cr = (lane >> 4) * 4, cc = lane & 15;
  #pragma unroll
  for (int mf = 0; mf < 2; mf++)
    #pragma unroll
    for (int nf = 0; nf < 2; nf++)
      #pragma unroll
      for (int qq = 0; qq < 4; qq++) {
        int row = m0 + wr*32 + mf*16 + cr + qq;
        int col = n0 + wcc*32 + nf*16 + cc;
        float vv = acc[mf][nf][qq];
        if (OUTBF) ((unsigned short*)Cp)[(size_t)row * N + col] = f2bf(vv);
        else       ((float*)Cp)[(size_t)row * N + col] = vv;
      }
}

// ---------------------------------------------------------------------------
// softmax over rows of logits[n*512+i][l], causal l<=i, scale 1/sqrt(512)
__global__ __launch_bounds__(256) void k4b_softmax(const float* __restrict__ logits,
                                                   unsigned short* __restrict__ probs) {
  __shared__ float red[4];
  __shared__ float red2[4];
  int m = blockIdx.x, t = threadIdx.x;
  int i = m & (SEQ - 1);
  const float scale = 0.04419417382415922f;   // 1/sqrt(512)
  const float NEG = -1e30f;
  float v0 = (t       <= i) ? logits[(size_t)m * SEQ + t      ] * scale : NEG;
  float v1 = (t + 256 <= i) ? logits[(size_t)m * SEQ + t + 256] * scale : NEG;
  float mx = fmaxf(v0, v1);
  #pragma unroll
  for (int off = 32; off; off >>= 1) mx = fmaxf(mx, __shfl_xor(mx, off));
  int w = t >> 6, lane = t & 63;
  if (lane == 0) red[w] = mx;
  __syncthreads();
  mx = fmaxf(fmaxf(red[0], red[1]), fmaxf(red[2], red[3]));
  float e0 = (t       <= i) ? __expf(v0 - mx) : 0.f;
  float e1 = (t + 256 <= i) ? __expf(v1 - mx) : 0.f;
  float s = e0 + e1;
  #pragma unroll
  for (int off = 32; off; off >>= 1) s += __shfl_xor(s, off);
  if (lane == 0) red2[w] = s;
  __syncthreads();
  s = red2[0] + red2[1] + red2[2] + red2[3];
  float inv = 1.f / s;
  probs[(size_t)m * SEQ + t]       = f2bf(e0 * inv);
  probs[(size_t)m * SEQ + t + 256] = f2bf(e1 * inv);
}

// ---------------------------------------------------------------------------
extern "C" void kernel_launch(void* const* d_in, const int* in_sizes, int n_in,
                              void* d_out, int out_size, void* d_ws, size_t ws_size,
                              hipStream_t stream) {
  (void)in_sizes; (void)n_in; (void)out_size; (void)ws_size;
  const float* q  = (const float*)d_in[0];
  const float* k  = (const float*)d_in[1];
  const float* v  = (const float*)d_in[2];
  const float* Wq = (const float*)d_in[3];
  const float* Wk = (const float*)d_in[4];
  const float* Wv = (const float*)d_in[5];
  float* out = (float*)d_out;

  char* ws = (char*)d_ws;
  size_t off = 0;
  auto alloc = [&](size_t bytes) -> void* {
    void* p = ws + off; off += (bytes + 255) & ~(size_t)255; return p;
  };
  float*          qpf    = (float*)         alloc((size_t)SEQ * DM * 4);
  unsigned short* qpb    = (unsigned short*)alloc((size_t)SEQ * DM * 2);
  unsigned short* kbf    = (unsigned short*)alloc((size_t)SEQ * DM * 2);
  unsigned short* vT     = (unsigned short*)alloc((size_t)DM * SEQ * 2);
  unsigned short* Wkb    = (unsigned short*)alloc((size_t)DM * DM * DM * 2);  // 32 MB
  unsigned short* Wvb    = (unsigned short*)alloc((size_t)DM * DM * DM * 2);  // 32 MB
  float*          af     = (float*)         alloc((size_t)NH * SEQ * DM * 4); // 4 MB
  unsigned short* abf    = (unsigned short*)alloc((size_t)NH * SEQ * DM * 2); // 2 MB
  float*          logits = (float*)         alloc((size_t)NH * SEQ * SEQ * 4);
  unsigned short* probs  = (unsigned short*)alloc((size_t)NH * SEQ * SEQ * 2);
  unsigned short* wbf    = (unsigned short*)alloc((size_t)NH * SEQ * DM * 2);

  hipMemsetAsync(af, 0, (size_t)NH * SEQ * DM * 4, stream);
  hipMemsetAsync(out, 0, (size_t)SEQ * DM * 4, stream);

  kconv<<<2048, 256, 0, stream>>>(Wk, Wkb);
  kconv<<<2048, 256, 0, stream>>>(Wv, Wvb);
  k0_convert<<<64, 256, 0, stream>>>(k, v, kbf, vT);
  k1_qproj<<<SEQ, 256, 0, stream>>>(q, Wq, qpf, qpb);
  // a: scale-in-A per-j GEMM at 4 blk/CU, f32 atomics (17.2 GFLOP)
  ka7<<<1024, 256, 0, stream>>>(Wkb, qpf, af);
  kconv<<<128, 256, 0, stream>>>(af, abf);   // af (f32) -> abf (bf16), 1M elems
  // logits = a @ kbf^T : M=4096, N=512, K=256
  gemm_small<0,0><<<512, 256, 0, stream>>>((const void*)abf, kbf, (void*)logits, NH*SEQ, SEQ, DM, 64);
  k4b_softmax<<<NH*SEQ, 256, 0, stream>>>(logits, probs);
  // w = probs @ v : M=4096, N=256, K=512 (B = vT)
  gemm_small<0,1><<<256, 256, 0, stream>>>((const void*)probs, vT, (void*)wbf, NH*SEQ, DM, SEQ, 64);
  // out: per-j GEMM + w-dot epilogue at 4+ blk/CU (17.2 GFLOP)
  ko7<<<1024, 256, 0, stream>>>(Wvb, qpb, wbf, out);
}

// Round 10
// 354.606 us; speedup vs baseline: 1.4799x; 1.4799x over previous
//
#include <hip/hip_runtime.h>
#include <hip/hip_bf16.h>
#include <math.h>

#define SEQ 512
#define DM  256
#define NH  8

typedef __attribute__((ext_vector_type(4))) float  f32x4;
typedef __attribute__((ext_vector_type(8))) __bf16 bf16x8;
typedef __attribute__((ext_vector_type(8))) short  s16x8;

__device__ __forceinline__ short fb(float x) {
  __bf16 h = (__bf16)x;
  return __builtin_bit_cast(short, h);
}
__device__ __forceinline__ unsigned short f2bf(float f) {
  unsigned int u = __builtin_bit_cast(unsigned int, f);
  u += 0x7fffu + ((u >> 16) & 1u);
  return (unsigned short)(u >> 16);
}
__device__ __forceinline__ float bf2f(unsigned short h) {
  unsigned int u = ((unsigned int)h) << 16;
  return __builtin_bit_cast(float, u);
}
__device__ __forceinline__ s16x8 cvt8(float4 a, float4 b) {
  s16x8 o;
  o[0]=fb(a.x); o[1]=fb(a.y); o[2]=fb(a.z); o[3]=fb(a.w);
  o[4]=fb(b.x); o[5]=fb(b.y); o[6]=fb(b.z); o[7]=fb(b.w);
  return o;
}
// async global->LDS, 16B/lane; dest is wave-uniform base (+lane*16 by HW)
__device__ __forceinline__ void gll16(const void* g, void* ldsbase) {
  __builtin_amdgcn_global_load_lds((const __attribute__((address_space(1))) void*)g,
                                   (__attribute__((address_space(3))) void*)ldsbase,
                                   16, 0, 0);
}

// ---------------------------------------------------------------------------
// kconv: f32 -> bf16 streaming convert (grid*256*32 elements)
__global__ __launch_bounds__(256) void kconv(const float* __restrict__ src,
                                             unsigned short* __restrict__ dst) {
  size_t base = ((size_t)blockIdx.x * 256 + threadIdx.x) * 32;
  #pragma unroll
  for (int u = 0; u < 4; u++) {
    float4 a = *(const float4*)(src + base + u * 8);
    float4 b = *(const float4*)(src + base + u * 8 + 4);
    *(s16x8*)(dst + base + u * 8) = cvt8(a, b);
  }
}

// ---------------------------------------------------------------------------
// K0: blocks 0..31 convert k (f32->bf16); blocks 32..63 transpose v -> vT bf16
__global__ __launch_bounds__(256) void k0_convert(const float* __restrict__ kin,
                                                  const float* __restrict__ vin,
                                                  unsigned short* __restrict__ kbf,
                                                  unsigned short* __restrict__ vT) {
  __shared__ unsigned short tl[64][72];
  int b = blockIdx.x, t = threadIdx.x;
  if (b < 32) {
    int base = b * 4096 + t * 16;
    float4 a0 = *(const float4*)(kin + base);
    float4 a1 = *(const float4*)(kin + base + 4);
    float4 a2 = *(const float4*)(kin + base + 8);
    float4 a3 = *(const float4*)(kin + base + 12);
    *(s16x8*)(kbf + base)     = cvt8(a0, a1);
    *(s16x8*)(kbf + base + 8) = cvt8(a2, a3);
  } else {
    int tb = b - 32;
    int i0 = (tb >> 2) * 64;
    int m0 = (tb & 3) * 64;
    int r = t >> 2, cq = t & 3;
    #pragma unroll
    for (int u = 0; u < 4; u++) {
      float4 x = *(const float4*)(vin + (size_t)(i0 + r) * DM + m0 + cq * 16 + u * 4);
      tl[cq*16 + u*4 + 0][r] = (unsigned short)fb(x.x);
      tl[cq*16 + u*4 + 1][r] = (unsigned short)fb(x.y);
      tl[cq*16 + u*4 + 2][r] = (unsigned short)fb(x.z);
      tl[cq*16 + u*4 + 3][r] = (unsigned short)fb(x.w);
    }
    __syncthreads();
    int mm = t >> 2;
    s16x8 w0, w1;
    #pragma unroll
    for (int e = 0; e < 8; e++) { w0[e] = tl[mm][cq*16 + e]; w1[e] = tl[mm][cq*16 + 8 + e]; }
    *(s16x8*)(vT + (size_t)(m0 + mm) * SEQ + i0 + cq * 16)     = w0;
    *(s16x8*)(vT + (size_t)(m0 + mm) * SEQ + i0 + cq * 16 + 8) = w1;
  }
}

// ---------------------------------------------------------------------------
// K1: qp = q @ Wq^T  (f32 + bf16 outputs)
__global__ __launch_bounds__(256) void k1_qproj(const float* __restrict__ q,
                                                const float* __restrict__ Wq,
                                                float* __restrict__ qpf,
                                                unsigned short* __restrict__ qpb) {
  __shared__ __align__(16) float qrow[DM];
  int i = blockIdx.x, t = threadIdx.x;
  if (t < 64) *(float4*)&qrow[t*4] = *(const float4*)(q + (size_t)i * DM + t * 4);
  __syncthreads();
  int w = t >> 6, lane = t & 63;
  for (int jj = 0; jj < 64; jj++) {
    int j = w * 64 + jj;
    float4 wv = *(const float4*)(Wq + (size_t)j * DM + lane * 4);
    float s = wv.x*qrow[lane*4] + wv.y*qrow[lane*4+1] + wv.z*qrow[lane*4+2] + wv.w*qrow[lane*4+3];
    #pragma unroll
    for (int off = 32; off; off >>= 1) s += __shfl_xor(s, off);
    if (lane == 0) { qpf[(size_t)i*DM + j] = s; qpb[(size_t)i*DM + j] = f2bf(s); }
  }
}

// ---------------------------------------------------------------------------
// ka8: r6 step-structure at 4 blocks/CU, NO register cap (r9 lesson: the
// (256,4) bound forced spills -> 540MB scratch traffic). Per block
// (head,jsplit,itile): 2 j's x 4 kt: {barrier; gll16 B 32KB (inv-swz src);
// stage scaled A (qp*qp[i,j] -> bf16, XOR-swz 8KB); barrier; 32 MFMA/wave}.
// Scale folded into A => acc accumulates across j. atomicAdd into f32 af
// (16-way per addr, lane-distinct). grid 1024 = head(8,XCD)|jsplit(16)|itile(8).
// LDS 40960 B -> 4 blocks/CU at VGPR<=128.
__global__ __launch_bounds__(256) void ka8(const unsigned short* __restrict__ Wkb,
                                           const float* __restrict__ qpf,
                                           float* __restrict__ af) {
  __shared__ __align__(16) unsigned short lB[256 * 64];   // 32KB, linear (gll16)
  __shared__ __align__(16) unsigned short lAc[64 * 64];   // 8KB, XOR-swizzled
  int bid = blockIdx.x;
  int head = bid & 7, rest = bid >> 3;
  int jsplit = rest >> 3, itile = rest & 7;          // jsplit 0..15
  int m0 = itile * 64;
  int t = threadIdx.x, w = t >> 6, lane = t & 63;
  int r = lane & 15, hi = lane >> 4;
  int srow = t >> 2, so = (t & 3) * 32;              // A-staging byte offsets
  const int jbase = head * 32 + jsplit * 2;

  f32x4 acc[4][4] = {};
  for (int jj = 0; jj < 2; jj++) {
    int jcol = jbase + jj;
    const unsigned short* Bj = Wkb + (size_t)jcol * 65536;
    for (int kt = 0; kt < 4; kt++) {
      __syncthreads();                               // prev reads done
      #pragma unroll
      for (int it = 0; it < 8; it++) {               // lB: 256x64 bf16
        int chunk = w * 8 + it;
        int row = chunk * 8 + (lane >> 3);
        int cb = ((lane & 7) * 16) ^ ((row & 7) << 4);
        gll16((const char*)(Bj + (size_t)row * 256 + kt * 64) + cb,
              (char*)lB + chunk * 1024);
      }
      { // stage scaled A: 64x64, qp*qp[i,jcol], f32->bf16, swz write
        float scal = qpf[(size_t)(m0 + srow) * DM + jcol];
        const float* src = qpf + (size_t)(m0 + srow) * DM + kt * 64 + (t & 3) * 16;
        float4 x0 = *(const float4*)src,       x1 = *(const float4*)(src + 4);
        float4 x2 = *(const float4*)(src + 8), x3 = *(const float4*)(src + 12);
        x0.x*=scal; x0.y*=scal; x0.z*=scal; x0.w*=scal;
        x1.x*=scal; x1.y*=scal; x1.z*=scal; x1.w*=scal;
        x2.x*=scal; x2.y*=scal; x2.z*=scal; x2.w*=scal;
        x3.x*=scal; x3.y*=scal; x3.z*=scal; x3.w*=scal;
        int swz = (srow & 7) << 4;
        *(s16x8*)((char*)lAc + srow*128 + (so ^ swz))        = cvt8(x0, x1);
        *(s16x8*)((char*)lAc + srow*128 + ((so + 16) ^ swz)) = cvt8(x2, x3);
      }
      __syncthreads();                               // drains vmcnt + lgkm
      #pragma unroll
      for (int kk = 0; kk < 2; kk++) {
        int kb = (kk*32 + hi*8) * 2;                 // byte col
        bf16x8 afr[4], bfr[4];
        #pragma unroll
        for (int mf = 0; mf < 4; mf++) {
          int row = mf*16 + r;
          afr[mf] = *(const bf16x8*)((const char*)lAc + row*128 + (kb ^ ((row & 7) << 4)));
        }
        #pragma unroll
        for (int nf = 0; nf < 4; nf++) {
          int bn = w*64 + nf*16 + r;
          bfr[nf] = *(const bf16x8*)((const char*)lB + bn*128 + (kb ^ ((bn & 7) << 4)));
        }
        #pragma unroll
        for (int mf = 0; mf < 4; mf++)
          #pragma unroll
          for (int nf = 0; nf < 4; nf++)
            acc[mf][nf] = __builtin_amdgcn_mfma_f32_16x16x32_bf16(afr[mf], bfr[nf], acc[mf][nf], 0, 0, 0);
      }
    }
  }
  #pragma unroll
  for (int mf = 0; mf < 4; mf++)
    #pragma unroll
    for (int nf = 0; nf < 4; nf++)
      #pragma unroll
      for (int qq = 0; qq < 4; qq++)
        atomicAdd(&af[((size_t)head * SEQ + m0 + mf*16 + hi*4 + qq) * DM + w*64 + nf*16 + r],
                  acc[mf][nf][qq]);
}

// ---------------------------------------------------------------------------
// ko8: r6 ko4 structure minus the 34KB lw (epilogue reads w from global,
// proven r9) -> LDS exactly 40960 B -> 4 blocks/CU. NO register cap.
// Per block: 2 j's x 4 kt: {barrier; gll16 B 32KB + gll16 A 8KB; barrier;
// 32 MFMA}; per-j epilogue: out[i,j] += sum_b U_j[i,b]*w (shfl + atomic).
// grid 1024 = head(8,XCD)|jsplit(16)|itile(8).
__global__ __launch_bounds__(256) void ko8(const unsigned short* __restrict__ Wvb,
                                           const unsigned short* __restrict__ qpb,
                                           const unsigned short* __restrict__ wbf,
                                           float* __restrict__ out) {
  __shared__ __align__(16) unsigned short lB[256 * 64];   // 32KB, linear (gll16)
  __shared__ __align__(16) unsigned short lA[64 * 64];    // 8KB,  linear (gll16)
  int bid = blockIdx.x;
  int head = bid & 7, rest = bid >> 3;
  int jsplit = rest >> 3, itile = rest & 7;
  int m0 = itile * 64;
  int t = threadIdx.x, w = t >> 6, lane = t & 63;
  int r = lane & 15, hi = lane >> 4;
  const int jbase = head * 32 + jsplit * 2;

  for (int jj = 0; jj < 2; jj++) {
    int jcol = jbase + jj;
    const unsigned short* Bj = Wvb + (size_t)jcol * 65536;
    f32x4 tmp[4][4] = {};
    for (int kt = 0; kt < 4; kt++) {
      __syncthreads();
      #pragma unroll
      for (int it = 0; it < 8; it++) {               // lB: 256x64
        int chunk = w * 8 + it;
        int row = chunk * 8 + (lane >> 3);
        int cb = ((lane & 7) * 16) ^ ((row & 7) << 4);
        gll16((const char*)(Bj + (size_t)row * 256 + kt * 64) + cb,
              (char*)lB + chunk * 1024);
      }
      #pragma unroll
      for (int it = 0; it < 2; it++) {               // lA: 64x64 from qpb
        int chunk = w * 2 + it;
        int row = chunk * 8 + (lane >> 3);
        int cb = ((lane & 7) * 16) ^ ((row & 7) << 4);
        gll16((const char*)(qpb + (size_t)(m0 + row) * 256 + kt * 64) + cb,
              (char*)lA + chunk * 1024);
      }
      __syncthreads();
      #pragma unroll
      for (int kk = 0; kk < 2; kk++) {
        int kb = (kk*32 + hi*8) * 2;
        bf16x8 afr[4], bfr[4];
        #pragma unroll
        for (int mf = 0; mf < 4; mf++) {
          int row = mf*16 + r;
          afr[mf] = *(const bf16x8*)((const char*)lA + row*128 + (kb ^ ((row & 7) << 4)));
        }
        #pragma unroll
        for (int nf = 0; nf < 4; nf++) {
          int bn = w*64 + nf*16 + r;
          bfr[nf] = *(const bf16x8*)((const char*)lB + bn*128 + (kb ^ ((bn & 7) << 4)));
        }
        #pragma unroll
        for (int mf = 0; mf < 4; mf++)
          #pragma unroll
          for (int nf = 0; nf < 4; nf++)
            tmp[mf][nf] = __builtin_amdgcn_mfma_f32_16x16x32_bf16(afr[mf], bfr[nf], tmp[mf][nf], 0, 0, 0);
      }
    }
    #pragma unroll
    for (int mf = 0; mf < 4; mf++)
      #pragma unroll
      for (int qq = 0; qq < 4; qq++) {
        int rloc = mf*16 + hi*4 + qq;
        const unsigned short* wrow = wbf + ((size_t)head * SEQ + m0 + rloc) * DM + w*64;
        float pp = 0.f;
        #pragma unroll
        for (int nf = 0; nf < 4; nf++)
          pp += tmp[mf][nf][qq] * bf2f(wrow[nf*16 + r]);
        pp += __shfl_xor(pp, 1);
        pp += __shfl_xor(pp, 2);
        pp += __shfl_xor(pp, 4);
        pp += __shfl_xor(pp, 8);
        if (r == 0) atomicAdd(&out[(size_t)(m0 + rloc) * DM + jcol], pp);
      }
  }
}

// ---------------------------------------------------------------------------
// Small 64x64-tile NT GEMM: C[M,N] = A[M,K] * B[N,K]^T, 4 waves (2x2)
template<int CONVA, int OUTBF>
__global__ __launch_bounds__(256) void gemm_small(const void* __restrict__ Ap,
                                                  const unsigned short* __restrict__ B,
                                                  void* __restrict__ Cp,
                                                  int M, int N, int K, int nMtiles) {
  __shared__ __align__(16) unsigned short lA[64 * 72];
  __shared__ __align__(16) unsigned short lB[64 * 72];
  int bid = blockIdx.x;
  int mtile = bid % nMtiles, ntile = bid / nMtiles;
  int m0 = mtile * 64, n0 = ntile * 64;
  int t = threadIdx.x, w = t >> 6, lane = t & 63;
  int wr = w >> 1, wcc = w & 1;
  f32x4 acc[2][2] = {};
  for (int kt = 0; kt < K; kt += 64) {
    __syncthreads();
    #pragma unroll
    for (int rep = 0; rep < 2; rep++) {
      int sc = rep * 256 + t;
      int row = sc >> 3, c8 = sc & 7;
      if (CONVA) {
        const float* src = (const float*)Ap + (size_t)(m0 + row) * K + kt + c8 * 8;
        float4 u0 = *(const float4*)src, u1 = *(const float4*)(src + 4);
        *(s16x8*)&lA[row * 72 + c8 * 8] = cvt8(u0, u1);
      } else {
        *(s16x8*)&lA[row * 72 + c8 * 8] =
            *(const s16x8*)((const unsigned short*)Ap + (size_t)(m0 + row) * K + kt + c8 * 8);
      }
      *(s16x8*)&lB[row * 72 + c8 * 8] = *(const s16x8*)(B + (size_t)(n0 + row) * K + kt + c8 * 8);
    }
    __syncthreads();
    #pragma unroll
    for (int kk = 0; kk < 2; kk++) {
      int r = lane & 15, kc = kk * 32 + (lane >> 4) * 8;
      bf16x8 afr[2], bfr[2];
      #pragma unroll
      for (int mf = 0; mf < 2; mf++) afr[mf] = *(const bf16x8*)&lA[(wr*32 + mf*16 + r) * 72 + kc];
      #pragma unroll
      for (int nf = 0; nf < 2; nf++) bfr[nf] = *(const bf16x8*)&lB[(wcc*32 + nf*16 + r) * 72 + kc];
      #pragma unroll
      for (int mf = 0; mf < 2; mf++)
        #pragma unroll
        for (int nf = 0; nf < 2; nf++)
          acc[mf][nf] = __builtin_amdgcn_mfma_f32_16x16x32_bf16(afr[mf], bfr[nf], acc[mf][nf], 0, 0, 0);
    }
  }
  int cr = (lane >> 4) * 4, cc = lane & 15;
  #pragma unroll
  for (int mf = 0; mf < 2; mf++)
    #pragma unroll
    for (int nf = 0; nf < 2; nf++)
      #pragma unroll
      for (int qq = 0; qq < 4; qq++) {
        int row = m0 + wr*32 + mf*16 + cr + qq;
        int col = n0 + wcc*32 + nf*16 + cc;
        float vv = acc[mf][nf][qq];
        if (OUTBF) ((unsigned short*)Cp)[(size_t)row * N + col] = f2bf(vv);
        else       ((float*)Cp)[(size_t)row * N + col] = vv;
      }
}

// ---------------------------------------------------------------------------
// softmax over rows of logits[n*512+i][l], causal l<=i, scale 1/sqrt(512)
__global__ __launch_bounds__(256) void k4b_softmax(const float* __restrict__ logits,
                                                   unsigned short* __restrict__ probs) {
  __shared__ float red[4];
  __shared__ float red2[4];
  int m = blockIdx.x, t = threadIdx.x;
  int i = m & (SEQ - 1);
  const float scale = 0.04419417382415922f;   // 1/sqrt(512)
  const float NEG = -1e30f;
  float v0 = (t       <= i) ? logits[(size_t)m * SEQ + t      ] * scale : NEG;
  float v1 = (t + 256 <= i) ? logits[(size_t)m * SEQ + t + 256] * scale : NEG;
  float mx = fmaxf(v0, v1);
  #pragma unroll
  for (int off = 32; off; off >>= 1) mx = fmaxf(mx, __shfl_xor(mx, off));
  int w = t >> 6, lane = t & 63;
  if (lane == 0) red[w] = mx;
  __syncthreads();
  mx = fmaxf(fmaxf(red[0], red[1]), fmaxf(red[2], red[3]));
  float e0 = (t       <= i) ? __expf(v0 - mx) : 0.f;
  float e1 = (t + 256 <= i) ? __expf(v1 - mx) : 0.f;
  float s = e0 + e1;
  #pragma unroll
  for (int off = 32; off; off >>= 1) s += __shfl_xor(s, off);
  if (lane == 0) red2[w] = s;
  __syncthreads();
  s = red2[0] + red2[1] + red2[2] + red2[3];
  float inv = 1.f / s;
  probs[(size_t)m * SEQ + t]       = f2bf(e0 * inv);
  probs[(size_t)m * SEQ + t + 256] = f2bf(e1 * inv);
}

// ---------------------------------------------------------------------------
extern "C" void kernel_launch(void* const* d_in, const int* in_sizes, int n_in,
                              void* d_out, int out_size, void* d_ws, size_t ws_size,
                              hipStream_t stream) {
  (void)in_sizes; (void)n_in; (void)out_size; (void)ws_size;
  const float* q  = (const float*)d_in[0];
  const float* k  = (const float*)d_in[1];
  const float* v  = (const float*)d_in[2];
  const float* Wq = (const float*)d_in[3];
  const float* Wk = (const float*)d_in[4];
  const float* Wv = (const float*)d_in[5];
  float* out = (float*)d_out;

  char* ws = (char*)d_ws;
  size_t off = 0;
  auto alloc = [&](size_t bytes) -> void* {
    void* p = ws + off; off += (bytes + 255) & ~(size_t)255; return p;
  };
  float*          qpf    = (float*)         alloc((size_t)SEQ * DM * 4);
  unsigned short* qpb    = (unsigned short*)alloc((size_t)SEQ * DM * 2);
  unsigned short* kbf    = (unsigned short*)alloc((size_t)SEQ * DM * 2);
  unsigned short* vT     = (unsigned short*)alloc((size_t)DM * SEQ * 2);
  unsigned short* Wkb    = (unsigned short*)alloc((size_t)DM * DM * DM * 2);  // 32 MB
  unsigned short* Wvb    = (unsigned short*)alloc((size_t)DM * DM * DM * 2);  // 32 MB
  float*          af     = (float*)         alloc((size_t)NH * SEQ * DM * 4); // 4 MB
  unsigned short* abf    = (unsigned short*)alloc((size_t)NH * SEQ * DM * 2); // 2 MB
  float*          logits = (float*)         alloc((size_t)NH * SEQ * SEQ * 4);
  unsigned short* probs  = (unsigned short*)alloc((size_t)NH * SEQ * SEQ * 2);
  unsigned short* wbf    = (unsigned short*)alloc((size_t)NH * SEQ * DM * 2);

  hipMemsetAsync(af, 0, (size_t)NH * SEQ * DM * 4, stream);
  hipMemsetAsync(out, 0, (size_t)SEQ * DM * 4, stream);

  kconv<<<2048, 256, 0, stream>>>(Wk, Wkb);
  kconv<<<2048, 256, 0, stream>>>(Wv, Wvb);
  k0_convert<<<64, 256, 0, stream>>>(k, v, kbf, vT);
  k1_qproj<<<SEQ, 256, 0, stream>>>(q, Wq, qpf, qpb);
  // a: scale-in-A per-j GEMM, 4 blk/CU, f32 atomics (17.2 GFLOP)
  ka8<<<1024, 256, 0, stream>>>(Wkb, qpf, af);
  kconv<<<128, 256, 0, stream>>>(af, abf);   // af (f32) -> abf (bf16)
  // logits = a @ kbf^T : M=4096, N=512, K=256
  gemm_small<0,0><<<512, 256, 0, stream>>>((const void*)abf, kbf, (void*)logits, NH*SEQ, SEQ, DM, 64);
  k4b_softmax<<<NH*SEQ, 256, 0, stream>>>(logits, probs);
  // w = probs @ v : M=4096, N=256, K=512 (B = vT)
  gemm_small<0,1><<<256, 256, 0, stream>>>((const void*)probs, vT, (void*)wbf, NH*SEQ, DM, SEQ, 64);
  // out: per-j GEMM + w-dot epilogue, 4 blk/CU (17.2 GFLOP)
  ko8<<<1024, 256, 0, stream>>>(Wvb, qpb, wbf, out);
}